// Round 14
// baseline (70.532 us; speedup 1.0000x reference)
//
#include <hip/hip_runtime.h>

#define Bb 8
#define Tt 512
#define Uu 128
#define U1 129
#define Vv 128

#define OUT_OFF 0                          // float2 OUT[b][t][u] linear
#define CTROW 132                          // floats per coeff row (129 used)
#define CTROWS 321                         // m = 0..320 (1..320 used)
#define CTASZ ((size_t)CTROWS * CTROW)
#define CT_BSZ (3 * CTASZ)                 // A,B,C per batch
#define CT_OFF ((size_t)Bb * Tt * U1 * 2)
#define CTCOL_OFF (CT_OFF + (size_t)Bb * CT_BSZ)       // float4 {A,B,C,0}[b][m]
#define RES_OFF (CTCOL_OFF + (size_t)Bb * CTROWS * 4)

#define K_LN2    0.6931471805599453f
#define K_INVLN2 1.4426950408889634f
#define SENT (-1.0e30f)                    // finite sentinel; exp2(-big)=0, no inf/NaN

__device__ __forceinline__ float fexp2(float x) {
    float r; asm("v_exp_f32 %0, %1" : "=v"(r) : "v"(x)); return r;
}
__device__ __forceinline__ float flog2(float x) {
    float r; asm("v_log_f32 %0, %1" : "=v"(r) : "v"(x)); return r;
}

// Stage A: band-restricted streaming LSE with 2-row-per-group MLP.
// Block (t,b) exits if t >= Tb; sweeps u <= Ub. Each 16-lane group handles TWO
// rows per iteration (4x float4 = 64B/lane in flight before any wait; two
// independent reductions interleaved) -> 2x memory-level parallelism vs r13.
// Wave reads 4KB contiguous per iter. OUT[b][t][u] = {log2 blank, log2 emit}.
__global__ __launch_bounds__(256) void lse_kernel(
    const float* __restrict__ logits, const int* __restrict__ y,
    const int* __restrict__ logit_lens, const int* __restrict__ y_lens,
    float* __restrict__ ws)
{
    const int b = blockIdx.y;
    const int t = blockIdx.x;
    if (t >= logit_lens[b]) return;
    const int Ue = y_lens[b];              // inclusive: rows u in [0, Ue]

    float2* outv = (float2*)(ws + OUT_OFF);
    const int wid  = threadIdx.x >> 6;
    const int lane = threadIdx.x & 63;
    const int g    = lane >> 4;            // group 0..3
    const int gl   = lane & 15;
    const unsigned rowbase = ((unsigned)b * Tt + t) * U1;
    const int yb = b * Uu;

    for (int u0 = wid * 8; u0 <= Ue; u0 += 32) {
        const int ua = u0 + g;             // group's first row
        const int ub = u0 + 4 + g;         // group's second row
        const int uca = ua > Ue ? Ue : ua; // clamp: redundant compute, guarded write
        const int ucb = ub > Ue ? Ue : ub;
        const float* pa = logits + (size_t)(rowbase + uca) * Vv;
        const float* pb = logits + (size_t)(rowbase + ucb) * Vv;
        float4 a1 = *(const float4*)(pa + gl * 4);
        float4 a2 = *(const float4*)(pa + 64 + gl * 4);
        float4 b1 = *(const float4*)(pb + gl * 4);
        float4 b2 = *(const float4*)(pb + 64 + gl * 4);

        float sa = (fexp2(a1.x * K_INVLN2) + fexp2(a1.y * K_INVLN2))
                 + (fexp2(a1.z * K_INVLN2) + fexp2(a1.w * K_INVLN2))
                 + (fexp2(a2.x * K_INVLN2) + fexp2(a2.y * K_INVLN2))
                 + (fexp2(a2.z * K_INVLN2) + fexp2(a2.w * K_INVLN2));
        float sb = (fexp2(b1.x * K_INVLN2) + fexp2(b1.y * K_INVLN2))
                 + (fexp2(b1.z * K_INVLN2) + fexp2(b1.w * K_INVLN2))
                 + (fexp2(b2.x * K_INVLN2) + fexp2(b2.y * K_INVLN2))
                 + (fexp2(b2.z * K_INVLN2) + fexp2(b2.w * K_INVLN2));
        #pragma unroll
        for (int off = 8; off; off >>= 1) {
            sa += __shfl_xor(sa, off);     // xor bits 0..3: stays in 16-group
            sb += __shfl_xor(sb, off);
        }
        float lseA = flog2(sa);
        float lseB = flog2(sb);

        float emA = SENT, emB = SENT;
        if (uca < Uu) {
            int yv = y[yb + uca];          // in [1, V); uniform per group
            int c = yv & 3;
            float4 cv = (yv & 64) ? a2 : a1;
            float cand = (c == 0) ? cv.x : (c == 1) ? cv.y : (c == 2) ? cv.z : cv.w;
            float ev = __shfl(cand, (lane & 48) | ((yv & 63) >> 2));
            emA = ev * K_INVLN2 - lseA;
        }
        if (ucb < Uu) {
            int yv = y[yb + ucb];
            int c = yv & 3;
            float4 cv = (yv & 64) ? b2 : b1;
            float cand = (c == 0) ? cv.x : (c == 1) ? cv.y : (c == 2) ? cv.z : cv.w;
            float ev = __shfl(cand, (lane & 48) | ((yv & 63) >> 2));
            emB = ev * K_INVLN2 - lseB;
        }
        if (gl == 0) {
            if (ua <= Ue) outv[rowbase + ua] = make_float2(a1.x * K_INVLN2 - lseA, emA);
            if (ub <= Ue) outv[rowbase + ub] = make_float2(b1.x * K_INVLN2 - lseB, emB);
        }
    }
}

__device__ __forceinline__ float lae2(float x, float y) {
    float dd = x - y;
    float nad = __builtin_bit_cast(float, __builtin_bit_cast(int, dd) | 0x80000000);
    return fmaxf(x, y) + flog2(1.0f + fexp2(nad));
}
__device__ __forceinline__ float lae3(float x, float y, float z) {
    float m = fmaxf(fmaxf(x, y), z);
    return m + flog2(fexp2(x - m) + fexp2(y - m) + fexp2(z - m));
}

// Stage B: pair-condensation coefficients (unchanged; early-exit past dend).
__global__ __launch_bounds__(256) void cond_kernel(
    const int* __restrict__ logit_lens, const int* __restrict__ y_lens,
    float* __restrict__ ws)
{
    const int b = blockIdx.x / 320;
    const int m = blockIdx.x - b * 320 + 1;
    if (m > ((logit_lens[b] - 1 + y_lens[b]) >> 1)) return;
    const int r1 = 2 * m - 2, r2 = 2 * m - 1;
    const float2* outv = (const float2*)(ws + OUT_OFF);

    __shared__ float2 D1[U1], D2[U1];
    for (int q = threadIdx.x; q < 2 * U1; q += 256) {
        const int which = q >= U1;
        const int j = q - which * U1;
        const int t = (which ? r2 : r1) - j;
        float2 val = make_float2(SENT, SENT);
        if (t >= 0 && t < Tt) val = outv[((size_t)b * Tt + t) * U1 + j];
        (which ? D2 : D1)[j] = val;
    }
    __syncthreads();

    const int u = threadIdx.x;
    if (u <= 128) {
        float2 d1  = D1[u], d2 = D2[u];
        float2 d1m = (u >= 1) ? D1[u - 1] : make_float2(SENT, SENT);
        float d2my  = (u >= 1) ? D2[u - 1].y : SENT;
        float d1m2y = (u >= 2) ? D1[u - 2].y : SENT;
        float A = d1.x + d2.x;
        float B = lae2(d1m.y + d2.x, d1m.x + d2my);
        float C = d1m2y + d2my;
        float* CTAb = ws + CT_OFF + (size_t)b * CT_BSZ;
        CTAb[(size_t)m * CTROW + u]             = A;
        CTAb[CTASZ + (size_t)m * CTROW + u]     = B;
        CTAb[2 * CTASZ + (size_t)m * CTROW + u] = C;
        if (u == 128)
            ((float4*)(ws + CTCOL_OFF))[(size_t)b * CTROWS + m] = make_float4(A, B, C, 0.0f);
    }
}

// rotate lane i <- lane i-1 (mod 64). MODE 0/1: DPP (runtime-verified), 2: shuffle.
template<int MODE>
__device__ __forceinline__ float rot1(float x, int lane) {
    if constexpr (MODE == 2) {
        float s = __shfl_up(x, 1);
        float w = __shfl(x, 63);
        return (lane == 0) ? w : s;
    } else {
        constexpr int CTRL = (MODE == 0) ? 0x13C : 0x134;
        int i = __builtin_bit_cast(int, x);
        i = __builtin_amdgcn_update_dpp(i, i, CTRL, 0xF, 0xF, true);
        return __builtin_bit_cast(float, i);
    }
}

template<int MODE, bool H128>
__device__ __forceinline__ void dp_body(int b, int lane, int Tb, int Ub,
                                        float* __restrict__ ws)
{
    const float2* outv = (const float2*)(ws + OUT_OFF);
    const float* CTAb = ws + CT_OFF + (size_t)b * CT_BSZ;
    const float* CTBb = CTAb + CTASZ;
    const float* CTCb = CTBb + CTASZ;
    const float4* COLb = (const float4*)(ws + CTCOL_OFF) + (size_t)b * CTROWS;
    int zv; asm volatile("v_mov_b32 %0, 0" : "=v"(zv));  // opaque 0: force VMEM

    float px = (lane == 0) ? 0.0f : SENT;
    float py = SENT, p2 = SENT;
    const int dend = Tb - 1 + Ub;      // in [319, 639]
    const int np   = dend >> 1;        // pairs (>=159)
    const int odd  = dend & 1;

    // tail/final loads issued up-front (latency hidden under the pair loop)
    float2 F1 = make_float2(0,0), F2 = make_float2(0,0), G = make_float2(0,0);
    if (odd) {
        const int r = dend - 1;
        int j1 = 2 * lane, j2 = 2 * lane + 1;
        int t1 = r - j1; t1 = t1 > Tt - 1 ? Tt - 1 : t1;   // clamp: out-of-lattice only
        int t2 = r - j2; t2 = t2 > Tt - 1 ? Tt - 1 : t2;
        F1 = outv[((size_t)b * Tt + t1) * U1 + j1];
        F2 = outv[((size_t)b * Tt + t2) * U1 + j2];
        if constexpr (H128) G = outv[((size_t)b * Tt + (r - 128)) * U1 + 128];
    }
    float pbf = outv[((size_t)b * Tt + (Tb - 1)) * U1 + Ub + zv].x;  // log2 blank final

    float2 A0,A1,A2,A3,A4,A5,A6,A7,A8,A9,A10,A11;
    float2 B0,B1,B2,B3,B4,B5,B6,B7,B8,B9,B10,B11;
    float2 C0,C1,C2,C3,C4,C5,C6,C7,C8,C9,C10,C11;
    float4 O0,O1,O2,O3,O4,O5,O6,O7,O8,O9,O10,O11;

#define LOADC(i, mm) { unsigned o = (unsigned)(mm) * CTROW + 2 * lane; \
    A##i = *(const float2*)(CTAb + o); \
    B##i = *(const float2*)(CTBb + o); \
    C##i = *(const float2*)(CTCb + o); \
    if constexpr (H128) O##i = COLb[(mm) + zv]; }

#define PIN(i) if constexpr (H128) { \
        asm volatile("" : "+v"(A##i.x), "+v"(A##i.y), "+v"(B##i.x), "+v"(B##i.y), \
                          "+v"(C##i.x), "+v"(C##i.y), "+v"(O##i.x), "+v"(O##i.y), "+v"(O##i.z)); \
    } else { \
        asm volatile("" : "+v"(A##i.x), "+v"(A##i.y), "+v"(B##i.x), "+v"(B##i.y), \
                          "+v"(C##i.x), "+v"(C##i.y)); \
    }

#define COMP2(i) { \
    float pm1 = rot1<MODE>(py, lane); \
    float pm0 = rot1<MODE>(px, lane); \
    float nx = lae3(px + A##i.x, pm1 + B##i.x, pm0 + C##i.x); \
    float ny = lae3(py + A##i.y, px + B##i.y, pm1 + C##i.y); \
    if constexpr (H128) p2 = lae3(p2 + O##i.x, pm1 + O##i.y, pm0 + O##i.z); \
    px = nx; py = ny; }

    LOADC(0,1)  LOADC(1,2)  LOADC(2,3)   LOADC(3,4)
    LOADC(4,5)  LOADC(5,6)  LOADC(6,7)   LOADC(7,8)
    LOADC(8,9)  LOADC(9,10) LOADC(10,11) LOADC(11,12)

    int m = 1;
    for (; m + 11 <= np; m += 12) {
        PIN(0)  COMP2(0)  { int dn = m + 12 > np ? np : m + 12; LOADC(0,  dn) }
        PIN(1)  COMP2(1)  { int dn = m + 13 > np ? np : m + 13; LOADC(1,  dn) }
        PIN(2)  COMP2(2)  { int dn = m + 14 > np ? np : m + 14; LOADC(2,  dn) }
        PIN(3)  COMP2(3)  { int dn = m + 15 > np ? np : m + 15; LOADC(3,  dn) }
        PIN(4)  COMP2(4)  { int dn = m + 16 > np ? np : m + 16; LOADC(4,  dn) }
        PIN(5)  COMP2(5)  { int dn = m + 17 > np ? np : m + 17; LOADC(5,  dn) }
        PIN(6)  COMP2(6)  { int dn = m + 18 > np ? np : m + 18; LOADC(6,  dn) }
        PIN(7)  COMP2(7)  { int dn = m + 19 > np ? np : m + 19; LOADC(7,  dn) }
        PIN(8)  COMP2(8)  { int dn = m + 20 > np ? np : m + 20; LOADC(8,  dn) }
        PIN(9)  COMP2(9)  { int dn = m + 21 > np ? np : m + 21; LOADC(9,  dn) }
        PIN(10) COMP2(10) { int dn = m + 22 > np ? np : m + 22; LOADC(10, dn) }
        PIN(11) COMP2(11) { int dn = m + 23 > np ? np : m + 23; LOADC(11, dn) }
    }
#define TAILC(i) if (m <= np) { PIN(i) COMP2(i) m++; }
    TAILC(0) TAILC(1) TAILC(2) TAILC(3) TAILC(4) TAILC(5)
    TAILC(6) TAILC(7) TAILC(8) TAILC(9) TAILC(10)

    if (odd) {   // single step diag dend-1 -> dend, operands direct from OUT
        float pm  = rot1<MODE>(py, lane);
        float pmE = rot1<MODE>(F2.y, lane);          // em(label 2l-1)
        float pmE0 = (lane == 0) ? SENT : pmE;       // u=0 has no left arm
        float nx = lae2(px + F1.x, pm + pmE0);
        float ny = lae2(py + F2.x, px + F1.y);
        if constexpr (H128) p2 = lae2(p2 + G.x, pm + pmE);   // lane0: pm=a(127), pmE=em(127)
        px = nx; py = ny;
    }

    float a;
    if constexpr (H128) {
        a = __shfl(p2, 0);
    } else {
        float ax = __shfl(px, Ub >> 1);
        float ay = __shfl(py, Ub >> 1);
        a = (Ub & 1) ? ay : ax;
    }
    if (lane == 0) {
        ws[RES_OFF + b] = -(a + pbf) * K_LN2;
    }
#undef LOADC
#undef PIN
#undef COMP2
#undef TAILC
}

__global__ __launch_bounds__(64) void dp_kernel(
    const int* __restrict__ logit_lens, const int* __restrict__ y_lens,
    float* __restrict__ ws)
{
    const int b = blockIdx.x;
    const int lane = threadIdx.x;
    const int Tb = logit_lens[b];
    const int Ub = y_lens[b];
    const bool h = (Ub == 128);
    int li = lane;
    int r0 = __builtin_amdgcn_update_dpp(li, li, 0x13C /*WAVE_ROR1*/, 0xF, 0xF, true);
    int r1 = __builtin_amdgcn_update_dpp(li, li, 0x134 /*WAVE_ROL1*/, 0xF, 0xF, true);
    int want = (lane + 63) & 63;
    if (__all(r0 == want)) {
        if (h) dp_body<0, true>(b, lane, Tb, Ub, ws);
        else   dp_body<0, false>(b, lane, Tb, Ub, ws);
    } else if (__all(r1 == want)) {
        if (h) dp_body<1, true>(b, lane, Tb, Ub, ws);
        else   dp_body<1, false>(b, lane, Tb, Ub, ws);
    } else {
        if (h) dp_body<2, true>(b, lane, Tb, Ub, ws);
        else   dp_body<2, false>(b, lane, Tb, Ub, ws);
    }
}

__global__ void mean_kernel(const float* __restrict__ res, float* __restrict__ out)
{
    if (threadIdx.x == 0) {
        float s = 0.0f;
        #pragma unroll
        for (int i = 0; i < Bb; ++i) s += res[i];
        out[0] = s * (1.0f / Bb);
    }
}

extern "C" void kernel_launch(void* const* d_in, const int* in_sizes, int n_in,
                              void* d_out, int out_size, void* d_ws, size_t ws_size,
                              hipStream_t stream) {
    const float* logits     = (const float*)d_in[0];
    const int*   y          = (const int*)d_in[1];
    const int*   logit_lens = (const int*)d_in[2];
    const int*   y_lens     = (const int*)d_in[3];
    float* ws  = (float*)d_ws;
    float* out = (float*)d_out;

    dim3 lgrid(Tt, Bb);
    lse_kernel<<<lgrid, 256, 0, stream>>>(logits, y, logit_lens, y_lens, ws);
    cond_kernel<<<Bb * 320, 256, 0, stream>>>(logit_lens, y_lens, ws);
    dp_kernel<<<Bb, 64, 0, stream>>>(logit_lens, y_lens, ws);
    mean_kernel<<<1, 64, 0, stream>>>(ws + RES_OFF, out);
}

// Round 15
// 69.453 us; speedup vs baseline: 1.0155x; 1.0155x over previous
//
#include <hip/hip_runtime.h>

#define Bb 8
#define Tt 512
#define Uu 128
#define U1 129
#define Vv 128

#define OUT_OFF 0                          // float2 OUT[b][t][u] linear
#define CTROWS 321                         // m = 0..320 (1..320 used)
#define PCKROW 512                         // floats per packed coeff row (64 lanes x 8)
#define PCKBSZ ((size_t)CTROWS * PCKROW)
#define PCK_OFF ((size_t)Bb * Tt * U1 * 2)
#define CTCOL_OFF (PCK_OFF + (size_t)Bb * PCKBSZ)      // float4 {A,B,C,0}[b][m] (u=128)
#define RES_OFF (CTCOL_OFF + (size_t)Bb * CTROWS * 4)

#define K_LN2    0.6931471805599453f
#define K_INVLN2 1.4426950408889634f
#define SENT (-1.0e30f)                    // finite sentinel; exp2(-big)=0, no inf/NaN

__device__ __forceinline__ float fexp2(float x) {
    float r; asm("v_exp_f32 %0, %1" : "=v"(r) : "v"(x)); return r;
}
__device__ __forceinline__ float flog2(float x) {
    float r; asm("v_log_f32 %0, %1" : "=v"(r) : "v"(x)); return r;
}
__device__ __forceinline__ float fmax3(float x, float y, float z) {
    float r; asm("v_max3_f32 %0, %1, %2, %3" : "=v"(r) : "v"(x), "v"(y), "v"(z));
    return r;
}

// Stage A: band-restricted streaming LSE (r14 structure; at its byte floor).
__global__ __launch_bounds__(256) void lse_kernel(
    const float* __restrict__ logits, const int* __restrict__ y,
    const int* __restrict__ logit_lens, const int* __restrict__ y_lens,
    float* __restrict__ ws)
{
    const int b = blockIdx.y;
    const int t = blockIdx.x;
    if (t >= logit_lens[b]) return;
    const int Ue = y_lens[b];              // inclusive: rows u in [0, Ue]

    float2* outv = (float2*)(ws + OUT_OFF);
    const int wid  = threadIdx.x >> 6;
    const int lane = threadIdx.x & 63;
    const int g    = lane >> 4;            // group 0..3
    const int gl   = lane & 15;
    const unsigned rowbase = ((unsigned)b * Tt + t) * U1;
    const int yb = b * Uu;

    for (int u0 = wid * 8; u0 <= Ue; u0 += 32) {
        const int ua = u0 + g;
        const int ub = u0 + 4 + g;
        const int uca = ua > Ue ? Ue : ua; // clamp: redundant compute, guarded write
        const int ucb = ub > Ue ? Ue : ub;
        const float* pa = logits + (size_t)(rowbase + uca) * Vv;
        const float* pb = logits + (size_t)(rowbase + ucb) * Vv;
        float4 a1 = *(const float4*)(pa + gl * 4);
        float4 a2 = *(const float4*)(pa + 64 + gl * 4);
        float4 b1 = *(const float4*)(pb + gl * 4);
        float4 b2 = *(const float4*)(pb + 64 + gl * 4);

        float sa = (fexp2(a1.x * K_INVLN2) + fexp2(a1.y * K_INVLN2))
                 + (fexp2(a1.z * K_INVLN2) + fexp2(a1.w * K_INVLN2))
                 + (fexp2(a2.x * K_INVLN2) + fexp2(a2.y * K_INVLN2))
                 + (fexp2(a2.z * K_INVLN2) + fexp2(a2.w * K_INVLN2));
        float sb = (fexp2(b1.x * K_INVLN2) + fexp2(b1.y * K_INVLN2))
                 + (fexp2(b1.z * K_INVLN2) + fexp2(b1.w * K_INVLN2))
                 + (fexp2(b2.x * K_INVLN2) + fexp2(b2.y * K_INVLN2))
                 + (fexp2(b2.z * K_INVLN2) + fexp2(b2.w * K_INVLN2));
        #pragma unroll
        for (int off = 8; off; off >>= 1) {
            sa += __shfl_xor(sa, off);     // xor bits 0..3: stays in 16-group
            sb += __shfl_xor(sb, off);
        }
        float lseA = flog2(sa);
        float lseB = flog2(sb);

        float emA = SENT, emB = SENT;
        if (uca < Uu) {
            int yv = y[yb + uca];          // in [1, V); uniform per group
            int c = yv & 3;
            float4 cv = (yv & 64) ? a2 : a1;
            float cand = (c == 0) ? cv.x : (c == 1) ? cv.y : (c == 2) ? cv.z : cv.w;
            float ev = __shfl(cand, (lane & 48) | ((yv & 63) >> 2));
            emA = ev * K_INVLN2 - lseA;
        }
        if (ucb < Uu) {
            int yv = y[yb + ucb];
            int c = yv & 3;
            float4 cv = (yv & 64) ? b2 : b1;
            float cand = (c == 0) ? cv.x : (c == 1) ? cv.y : (c == 2) ? cv.z : cv.w;
            float ev = __shfl(cand, (lane & 48) | ((yv & 63) >> 2));
            emB = ev * K_INVLN2 - lseB;
        }
        if (gl == 0) {
            if (ua <= Ue) outv[rowbase + ua] = make_float2(a1.x * K_INVLN2 - lseA, emA);
            if (ub <= Ue) outv[rowbase + ub] = make_float2(b1.x * K_INVLN2 - lseB, emB);
        }
    }
}

__device__ __forceinline__ float lae2(float x, float y) {
    float dd = x - y;
    float nad = __builtin_bit_cast(float, __builtin_bit_cast(int, dd) | 0x80000000);
    return fmaxf(x, y) + flog2(1.0f + fexp2(nad));
}
__device__ __forceinline__ float lae3(float x, float y, float z) {
    float m = fmax3(x, y, z);
    return m + flog2(fexp2(x - m) + fexp2(y - m) + fexp2(z - m));
}

// Stage B: pair-condensation coefficients, PACKED for dp's load path.
// Per (b, m): record for lane l = {A(2l),A(2l+1),B(2l),B(2l+1),C(2l),C(2l+1),0,0}
// (32B, aligned) -> dp reads 1 float4 + 1 float2 per lane, 2KB contiguous/row.
// u=128 coefficients go to the separate COL float4 (H128 batches only).
__global__ __launch_bounds__(256) void cond_kernel(
    const int* __restrict__ logit_lens, const int* __restrict__ y_lens,
    float* __restrict__ ws)
{
    const int b = blockIdx.x / 320;
    const int m = blockIdx.x - b * 320 + 1;
    if (m > ((logit_lens[b] - 1 + y_lens[b]) >> 1)) return;
    const int r1 = 2 * m - 2, r2 = 2 * m - 1;
    const float2* outv = (const float2*)(ws + OUT_OFF);

    __shared__ float2 D1[U1], D2[U1];
    __shared__ float pckS[PCKROW];
    for (int q = threadIdx.x; q < 2 * U1; q += 256) {
        const int which = q >= U1;
        const int j = q - which * U1;
        const int t = (which ? r2 : r1) - j;
        float2 val = make_float2(SENT, SENT);
        if (t >= 0 && t < Tt) val = outv[((size_t)b * Tt + t) * U1 + j];
        (which ? D2 : D1)[j] = val;
    }
    __syncthreads();

    const int u = threadIdx.x;
    if (u <= 128) {
        float2 d1  = D1[u], d2 = D2[u];
        float2 d1m = (u >= 1) ? D1[u - 1] : make_float2(SENT, SENT);
        float d2my  = (u >= 1) ? D2[u - 1].y : SENT;
        float d1m2y = (u >= 2) ? D1[u - 2].y : SENT;
        float A = d1.x + d2.x;
        float B = lae2(d1m.y + d2.x, d1m.x + d2my);
        float C = d1m2y + d2my;
        if (u < 128) {
            int base = (u >> 1) * 8 + (u & 1);
            pckS[base]     = A;
            pckS[base + 2] = B;
            pckS[base + 4] = C;
            if ((u & 1) == 0) { pckS[base + 6] = 0.0f; pckS[base + 7] = 0.0f; }
        } else {
            ((float4*)(ws + CTCOL_OFF))[(size_t)b * CTROWS + m] = make_float4(A, B, C, 0.0f);
        }
    }
    __syncthreads();

    float* pckG = ws + PCK_OFF + (size_t)b * PCKBSZ + (size_t)m * PCKROW;
    for (int i = threadIdx.x; i < PCKROW; i += 256) pckG[i] = pckS[i];
}

// rotate lane i <- lane i-1 (mod 64). MODE 0/1: DPP (runtime-verified), 2: shuffle.
template<int MODE>
__device__ __forceinline__ float rot1(float x, int lane) {
    if constexpr (MODE == 2) {
        float s = __shfl_up(x, 1);
        float w = __shfl(x, 63);
        return (lane == 0) ? w : s;
    } else {
        constexpr int CTRL = (MODE == 0) ? 0x13C : 0x134;
        int i = __builtin_bit_cast(int, x);
        i = __builtin_amdgcn_update_dpp(i, i, CTRL, 0xF, 0xF, true);
        return __builtin_bit_cast(float, i);
    }
}

template<int MODE, bool H128>
__device__ __forceinline__ void dp_body(int b, int lane, int Tb, int Ub,
                                        float* __restrict__ ws)
{
    const float2* outv = (const float2*)(ws + OUT_OFF);
    const float* PCKb = ws + PCK_OFF + (size_t)b * PCKBSZ;
    const float4* COLb = (const float4*)(ws + CTCOL_OFF) + (size_t)b * CTROWS;
    int zv; asm volatile("v_mov_b32 %0, 0" : "=v"(zv));  // opaque 0: force VMEM

    float px = (lane == 0) ? 0.0f : SENT;
    float py = SENT, p2 = SENT;
    const int dend = Tb - 1 + Ub;      // in [319, 639]
    const int np   = dend >> 1;        // pairs (>=159)
    const int odd  = dend & 1;

    // tail/final loads issued up-front (latency hidden under the pair loop)
    float2 F1 = make_float2(0,0), F2 = make_float2(0,0), G = make_float2(0,0);
    if (odd) {
        const int r = dend - 1;
        int j1 = 2 * lane, j2 = 2 * lane + 1;
        int t1 = r - j1; t1 = t1 > Tt - 1 ? Tt - 1 : t1;   // clamp: out-of-lattice only
        int t2 = r - j2; t2 = t2 > Tt - 1 ? Tt - 1 : t2;
        F1 = outv[((size_t)b * Tt + t1) * U1 + j1];
        F2 = outv[((size_t)b * Tt + t2) * U1 + j2];
        if constexpr (H128) G = outv[((size_t)b * Tt + (r - 128)) * U1 + 128];
    }
    float pbf = outv[((size_t)b * Tt + (Tb - 1)) * U1 + Ub + zv].x;  // log2 blank final

    float4 Q0,Q1,Q2,Q3,Q4,Q5,Q6,Q7,Q8,Q9,Q10,Q11,Q12,Q13,Q14,Q15;
    float2 R0,R1,R2,R3,R4,R5,R6,R7,R8,R9,R10,R11,R12,R13,R14,R15;
    float4 O0,O1,O2,O3,O4,O5,O6,O7,O8,O9,O10,O11,O12,O13,O14,O15;

#define LOADC(i, mm) { unsigned o = (unsigned)(mm) * PCKROW + (lane << 3); \
    Q##i = *(const float4*)(PCKb + o); \
    R##i = *(const float2*)(PCKb + o + 4); \
    if constexpr (H128) O##i = COLb[(mm) + zv]; }

#define PIN(i) if constexpr (H128) { \
        asm volatile("" : "+v"(Q##i.x), "+v"(Q##i.y), "+v"(Q##i.z), "+v"(Q##i.w), \
                          "+v"(R##i.x), "+v"(R##i.y), "+v"(O##i.x), "+v"(O##i.y), "+v"(O##i.z)); \
    } else { \
        asm volatile("" : "+v"(Q##i.x), "+v"(Q##i.y), "+v"(Q##i.z), "+v"(Q##i.w), \
                          "+v"(R##i.x), "+v"(R##i.y)); \
    }

    // slot u=2l: arms {u,A}, {u-1,B}, {u-2,C}; slot u=2l+1: {u,A}, {u-1,B}, {u-2,C}
#define COMP2(i) { \
    float pm1 = rot1<MODE>(py, lane); \
    float pm0 = rot1<MODE>(px, lane); \
    float nx = lae3(px + Q##i.x, pm1 + Q##i.z, pm0 + R##i.x); \
    float ny = lae3(py + Q##i.y, px + Q##i.w, pm1 + R##i.y); \
    if constexpr (H128) p2 = lae3(p2 + O##i.x, pm1 + O##i.y, pm0 + O##i.z); \
    px = nx; py = ny; }

    LOADC(0,1)   LOADC(1,2)   LOADC(2,3)   LOADC(3,4)
    LOADC(4,5)   LOADC(5,6)   LOADC(6,7)   LOADC(7,8)
    LOADC(8,9)   LOADC(9,10)  LOADC(10,11) LOADC(11,12)
    LOADC(12,13) LOADC(13,14) LOADC(14,15) LOADC(15,16)

    int m = 1;
    for (; m + 15 <= np; m += 16) {
        PIN(0)  COMP2(0)  { int dn = m + 16 > np ? np : m + 16; LOADC(0,  dn) }
        PIN(1)  COMP2(1)  { int dn = m + 17 > np ? np : m + 17; LOADC(1,  dn) }
        PIN(2)  COMP2(2)  { int dn = m + 18 > np ? np : m + 18; LOADC(2,  dn) }
        PIN(3)  COMP2(3)  { int dn = m + 19 > np ? np : m + 19; LOADC(3,  dn) }
        PIN(4)  COMP2(4)  { int dn = m + 20 > np ? np : m + 20; LOADC(4,  dn) }
        PIN(5)  COMP2(5)  { int dn = m + 21 > np ? np : m + 21; LOADC(5,  dn) }
        PIN(6)  COMP2(6)  { int dn = m + 22 > np ? np : m + 22; LOADC(6,  dn) }
        PIN(7)  COMP2(7)  { int dn = m + 23 > np ? np : m + 23; LOADC(7,  dn) }
        PIN(8)  COMP2(8)  { int dn = m + 24 > np ? np : m + 24; LOADC(8,  dn) }
        PIN(9)  COMP2(9)  { int dn = m + 25 > np ? np : m + 25; LOADC(9,  dn) }
        PIN(10) COMP2(10) { int dn = m + 26 > np ? np : m + 26; LOADC(10, dn) }
        PIN(11) COMP2(11) { int dn = m + 27 > np ? np : m + 27; LOADC(11, dn) }
        PIN(12) COMP2(12) { int dn = m + 28 > np ? np : m + 28; LOADC(12, dn) }
        PIN(13) COMP2(13) { int dn = m + 29 > np ? np : m + 29; LOADC(13, dn) }
        PIN(14) COMP2(14) { int dn = m + 30 > np ? np : m + 30; LOADC(14, dn) }
        PIN(15) COMP2(15) { int dn = m + 31 > np ? np : m + 31; LOADC(15, dn) }
    }
#define TAILC(i) if (m <= np) { PIN(i) COMP2(i) m++; }
    TAILC(0)  TAILC(1)  TAILC(2)  TAILC(3)  TAILC(4)
    TAILC(5)  TAILC(6)  TAILC(7)  TAILC(8)  TAILC(9)
    TAILC(10) TAILC(11) TAILC(12) TAILC(13) TAILC(14)

    if (odd) {   // single step diag dend-1 -> dend, operands direct from OUT
        float pm  = rot1<MODE>(py, lane);
        float pmE = rot1<MODE>(F2.y, lane);          // em(label 2l-1)
        float pmE0 = (lane == 0) ? SENT : pmE;       // u=0 has no left arm
        float nx = lae2(px + F1.x, pm + pmE0);
        float ny = lae2(py + F2.x, px + F1.y);
        if constexpr (H128) p2 = lae2(p2 + G.x, pm + pmE);   // lane0: pm=a(127), pmE=em(127)
        px = nx; py = ny;
    }

    float a;
    if constexpr (H128) {
        a = __shfl(p2, 0);
    } else {
        float ax = __shfl(px, Ub >> 1);
        float ay = __shfl(py, Ub >> 1);
        a = (Ub & 1) ? ay : ax;
    }
    if (lane == 0) {
        ws[RES_OFF + b] = -(a + pbf) * K_LN2;
    }
#undef LOADC
#undef PIN
#undef COMP2
#undef TAILC
}

__global__ __launch_bounds__(64) void dp_kernel(
    const int* __restrict__ logit_lens, const int* __restrict__ y_lens,
    float* __restrict__ ws)
{
    const int b = blockIdx.x;
    const int lane = threadIdx.x;
    const int Tb = logit_lens[b];
    const int Ub = y_lens[b];
    const bool h = (Ub == 128);
    int li = lane;
    int r0 = __builtin_amdgcn_update_dpp(li, li, 0x13C /*WAVE_ROR1*/, 0xF, 0xF, true);
    int r1 = __builtin_amdgcn_update_dpp(li, li, 0x134 /*WAVE_ROL1*/, 0xF, 0xF, true);
    int want = (lane + 63) & 63;
    if (__all(r0 == want)) {
        if (h) dp_body<0, true>(b, lane, Tb, Ub, ws);
        else   dp_body<0, false>(b, lane, Tb, Ub, ws);
    } else if (__all(r1 == want)) {
        if (h) dp_body<1, true>(b, lane, Tb, Ub, ws);
        else   dp_body<1, false>(b, lane, Tb, Ub, ws);
    } else {
        if (h) dp_body<2, true>(b, lane, Tb, Ub, ws);
        else   dp_body<2, false>(b, lane, Tb, Ub, ws);
    }
}

__global__ void mean_kernel(const float* __restrict__ res, float* __restrict__ out)
{
    if (threadIdx.x == 0) {
        float s = 0.0f;
        #pragma unroll
        for (int i = 0; i < Bb; ++i) s += res[i];
        out[0] = s * (1.0f / Bb);
    }
}

extern "C" void kernel_launch(void* const* d_in, const int* in_sizes, int n_in,
                              void* d_out, int out_size, void* d_ws, size_t ws_size,
                              hipStream_t stream) {
    const float* logits     = (const float*)d_in[0];
    const int*   y          = (const int*)d_in[1];
    const int*   logit_lens = (const int*)d_in[2];
    const int*   y_lens     = (const int*)d_in[3];
    float* ws  = (float*)d_ws;
    float* out = (float*)d_out;

    dim3 lgrid(Tt, Bb);
    lse_kernel<<<lgrid, 256, 0, stream>>>(logits, y, logit_lens, y_lens, ws);
    cond_kernel<<<Bb * 320, 256, 0, stream>>>(logit_lens, y_lens, ws);
    dp_kernel<<<Bb, 64, 0, stream>>>(logit_lens, y_lens, ws);
    mean_kernel<<<1, 64, 0, stream>>>(ws + RES_OFF, out);
}